// Round 6
// baseline (86.574 us; speedup 1.0000x reference)
//
#include <hip/hip_runtime.h>

#define NPTS 4096      // points per cloud
#define NB   4         // batch
#define KP   512       // keypoints
#define HUBER_C 0.01f
#define BT     512                 // threads per main block
#define QCHUNK 128                 // queries per gal block
#define NQC (NPTS / QCHUNK)        // 32
#define GAL_BLOCKS (2 * NB * NQC)  // 256
#define NPK (NPTS / 2)             // 2048 o-pair packs
#define QL  8                      // query lanes (per o-group)
#define NOG (BT / QL)              // 64 o-groups
#define PKG (NPK / NOG)            // 32 packs per group
#define QPT (QCHUNK / QL)          // 16 queries per thread
#define LDA_STRIDE (PKG + 1)       // 33: +16B per group -> 4-bank phase shift

typedef float v2f __attribute__((ext_vector_type(2)));

// Tuning log (MI355X):
//   R9: distributed finalize w/ __threadfence() -> 155.3. LESSON:
//     __threadfence on gfx950 = buffer_wbl2/inv; serialized the chip.
//   R10: fences removed -> 122.1, main 53.7us. DIAGNOSIS: 2M device-scope
//     atomicMin stream was the cost (WRITE 8.4MB @ ~200GB/s effective).
//   R11: per-block full scan, 1 atomicAdd/block -> 95.0, main ~27us.
//     DIAGNOSIS: LDS-issue bound (2.1M ds_read_b128, 1 query/thread).
//   R12: 8 queries/thread (DS instrs /8) -> 85.2, main ~17us (inferred
//     vs ~68us fixed harness-fill window). Remaining: DS 5.1us +
//     VALU 4.3us un-overlapped at 1 wave/SIMD; elementwise_min on v2f
//     = 2 scalar v_min (no v_pk_min_f32 on gfx950).
//   R13 (this): QPT=16 (DS 512/CU ~2.6us), og-octet min via 3 shfl_xor
//     (kills 32KB pmin array), 2-pack min3 pairing (2.0 instr/dist),
//     BT=512 (2 waves/SIMD so DS hides under VALU). Budget ~6us.

// ---------------- helpers ----------------

__device__ inline float huber_f(float x) {
    return (x < HUBER_C) ? 0.5f * x * x
                         : fmaf(HUBER_C, x, -0.5f * HUBER_C * HUBER_C);
}

__device__ inline v2f splat2(float s) { v2f r; r.x = s; r.y = s; return r; }

// ---------------- kernels ----------------

__global__ void init_kernel(float* __restrict__ out) {
    if (threadIdx.x < 2) out[threadIdx.x] = 0.0f;
}

// Fused: [0,GAL_BLOCKS) gal; then knn; then kp.
// Every block ends with one atomicAdd into out[0] or out[1].
__global__ __launch_bounds__(BT, 2) void main_kernel(
    const float* __restrict__ srcT, const float* __restrict__ tgtT,
    const float* __restrict__ skp, const float* __restrict__ tkp,
    const float* __restrict__ R, const float* __restrict__ T,
    const float* __restrict__ aknn, const float* __restrict__ bknn,
    const int* __restrict__ kptr, float* __restrict__ out,
    int knn_blocks, int knn_quads)
{
    __shared__ float4 lds_a[NOG * LDA_STRIDE];  // {x0,x1,y0,y1} per o-pair
    __shared__ float4 lds_b[NOG * LDA_STRIDE];  // {z0,z1,w0,w1} per o-pair
    __shared__ float4 qlds4[QCHUNK];            // {-2x,-2y,-2z,|q|^2}
    __shared__ float pm[BT / 64][QCHUNK + 4];   // per-wave partial mins
    __shared__ float red[BT / 64];

    const int bid = blockIdx.x;
    const int tid = threadIdx.x;
    float contrib = 0.0f;
    float* target;

    if (bid < GAL_BLOCKS) {
        // ---- global-align: 128 queries/block, 64-way o-split ----
        const int qc  = bid & (NQC - 1);
        const int b   = (bid >> 5) & 3;
        const int dir = bid >> 7;             // 0: queries=src, 1: queries=tgt
        const float* qb = (dir ? tgtT : srcT) + b * 3 * NPTS;
        const float* ob = (dir ? srcT : tgtT) + b * 3 * NPTS;

        // stage whole other-cloud into LDS, pair-packed, group-padded
        #pragma unroll
        for (int k = 0; k < NPK / BT; ++k) {           // 4 iters
            int idx = tid + k * BT;
            int j = 2 * idx;
            float2 X = *(const float2*)(ob + j);
            float2 Y = *(const float2*)(ob + NPTS + j);
            float2 Z = *(const float2*)(ob + 2 * NPTS + j);
            float w0 = fmaf(X.x, X.x, fmaf(Y.x, Y.x, Z.x * Z.x));
            float w1 = fmaf(X.y, X.y, fmaf(Y.y, Y.y, Z.y * Z.y));
            int li = idx + (idx >> 5);                 // PKG=32 group pad
            lds_a[li] = make_float4(X.x, X.y, Y.x, Y.y);
            lds_b[li] = make_float4(Z.x, Z.y, w0, w1);
        }
        // stage this block's 128 queries (pre-negated-doubled + norm)
        if (tid < QCHUNK) {
            int q = qc * QCHUNK + tid;
            float x = qb[q], y = qb[NPTS + q], z = qb[2 * NPTS + q];
            qlds4[tid] = make_float4(-2.0f * x, -2.0f * y, -2.0f * z,
                                     fmaf(x, x, fmaf(y, y, z * z)));
        }
        __syncthreads();

        // 16 queries per thread in registers
        const int ql0 = tid & (QL - 1);
        const int og  = tid >> 3;                      // [0, 64)
        float ax[QPT], ay[QPT], az[QPT], qw[QPT];
        v2f mm[QPT];
        #pragma unroll
        for (int j2 = 0; j2 < QPT; ++j2) {
            float4 Q = qlds4[ql0 + QL * j2];
            ax[j2] = Q.x; ay[j2] = Q.y; az[j2] = Q.z; qw[j2] = Q.w;
            mm[j2].x = 3.0e38f; mm[j2].y = 3.0e38f;
        }

        // inner scan: per 2 packs, 4 ds_read_b128 feed 16q x 4o = 64 dists
        const float4* la = lds_a + og * LDA_STRIDE;
        const float4* lb = lds_b + og * LDA_STRIDE;
        auto dist2 = [&](const float4& A, const float4& B, int j2) -> v2f {
            v2f X, Y, Z, W;
            X.x = A.x; X.y = A.y; Y.x = A.z; Y.y = A.w;
            Z.x = B.x; Z.y = B.y; W.x = B.z; W.y = B.w;
            return __builtin_elementwise_fma(X, splat2(ax[j2]),
                   __builtin_elementwise_fma(Y, splat2(ay[j2]),
                   __builtin_elementwise_fma(Z, splat2(az[j2]), W)));
        };
        #pragma unroll 2
        for (int p = 0; p < PKG; p += 2) {
            float4 A0 = la[p], B0 = lb[p];
            float4 A1 = la[p + 1], B1 = lb[p + 1];
            #pragma unroll
            for (int j2 = 0; j2 < QPT; ++j2) {
                v2f t0 = dist2(A0, B0, j2);
                v2f t1 = dist2(A1, B1, j2);
                mm[j2].x = fminf(fminf(mm[j2].x, t0.x), t1.x);  // v_min3
                mm[j2].y = fminf(fminf(mm[j2].y, t0.y), t1.y);
            }
        }

        // og-octet reduce in-wave: og = lane bits 3..5 -> xor 8/16/32
        const int lane = tid & 63;
        const int w = tid >> 6;
        #pragma unroll
        for (int j2 = 0; j2 < QPT; ++j2) {
            float v = fminf(mm[j2].x, mm[j2].y);
            v = fminf(v, __shfl_xor(v, 8, 64));
            v = fminf(v, __shfl_xor(v, 16, 64));
            v = fminf(v, __shfl_xor(v, 32, 64));
            if (lane < QL) pm[w][ql0 + QL * j2] = v + qw[j2];
        }
        __syncthreads();

        if (tid < QCHUNK) {
            float m = 3.0e38f;
            #pragma unroll
            for (int w2 = 0; w2 < BT / 64; ++w2)
                m = fminf(m, pm[w2][tid]);
            contrib = huber_f(m);
        }
        target = out + 1;
    } else if (bid < GAL_BLOCKS + knn_blocks) {
        // ---- knn consensus: sum((a-b)^2)/k ----
        int i = (bid - GAL_BLOCKS) * BT + tid;
        if (i < knn_quads) {
            float4 va = ((const float4*)aknn)[i];
            float4 vb = ((const float4*)bknn)[i];
            float dx = va.x - vb.x, dy = va.y - vb.y;
            float dz = va.z - vb.z, dw = va.w - vb.w;
            contrib = fmaf(dx, dx, fmaf(dy, dy, fmaf(dz, dz, dw * dw)));
        }
        contrib *= 1.0f / (float)(*kptr);
        target = out;
    } else {
        // ---- keypoints: sum((R@s + t - g)^2) ----
        int i = (bid - GAL_BLOCKS - knn_blocks) * BT + tid;   // [0, NB*KP)
        int b = i >> 9;
        int n = i & (KP - 1);
        const float* r = R + b * 9;
        const float* t = T + b * 3;
        const float* s = skp + b * 3 * KP;
        const float* g = tkp + b * 3 * KP;
        float sx = s[n], sy = s[KP + n], sz = s[2 * KP + n];
        #pragma unroll
        for (int d = 0; d < 3; ++d) {
            float v = fmaf(r[d*3+0], sx, fmaf(r[d*3+1], sy, fmaf(r[d*3+2], sz, t[d])))
                      - g[d * KP + n];
            contrib = fmaf(v, v, contrib);
        }
        target = out;
    }

    // ---- block-wide sum -> single atomicAdd ----
    float v = contrib;
    #pragma unroll
    for (int off = 32; off; off >>= 1) v += __shfl_down(v, off, 64);
    if ((tid & 63) == 0) red[tid >> 6] = v;
    __syncthreads();
    if (tid == 0) {
        float s = 0.0f;
        #pragma unroll
        for (int w2 = 0; w2 < BT / 64; ++w2) s += red[w2];
        atomicAdd(target, s);
    }
}

// ---------------- launch ----------------

extern "C" void kernel_launch(void* const* d_in, const int* in_sizes, int n_in,
                              void* d_out, int out_size, void* d_ws, size_t ws_size,
                              hipStream_t stream) {
    const float* skp  = (const float*)d_in[0];   // (B,3,KP)
    const float* tkp  = (const float*)d_in[1];   // (B,3,KP)
    const float* R    = (const float*)d_in[2];   // (B,3,3)
    const float* T    = (const float*)d_in[3];   // (B,3)
    const float* aknn = (const float*)d_in[4];   // (B,3,KP,K)
    const float* bknn = (const float*)d_in[5];   // (B,3,KP,K)
    const int*   kptr = (const int*)d_in[6];     // scalar k
    const float* srcT = (const float*)d_in[7];   // (B,3,N)
    const float* tgtT = (const float*)d_in[8];   // (B,3,N)
    float* out = (float*)d_out;

    const int knn_quads  = in_sizes[4] / 4;                   // 49152
    const int knn_blocks = (knn_quads + BT - 1) / BT;         // 96
    const int kp_blocks  = (NB * KP + BT - 1) / BT;           // 4
    const int total      = GAL_BLOCKS + knn_blocks + kp_blocks;   // 356

    init_kernel<<<1, 64, 0, stream>>>(out);
    main_kernel<<<total, BT, 0, stream>>>(
        srcT, tgtT, skp, tkp, R, T, aknn, bknn, kptr, out,
        knn_blocks, knn_quads);
}